// Round 13
// baseline (166.097 us; speedup 1.0000x reference)
//
#include <hip/hip_runtime.h>

#define DD 256   // feature dim
#define N1 512
#define N2 512
#define BB 4

// Packed fp32: gfx950 (gfx90a+) PackedFP32Ops; the compiler selects
// v_pk_{add,mul,fma}_f32 from <2 x float> vector IR.
typedef float f2 __attribute__((ext_vector_type(2)));

// ---------------------------------------------------------------------------
// Kernel 1: projection GEMMs. R2 version verbatim: 32x64 tile / 256 threads /
// 2x4 register blocking (packed), K-chunks of 32, register-prefetch double
// buffering, 512 blocks = 2/CU. Proven; leave alone.
// ---------------------------------------------------------------------------
__global__ __launch_bounds__(256) void proj_kernel(
    const float* __restrict__ x, const float* __restrict__ y,
    const float* __restrict__ W1, const float* __restrict__ b1,
    float* __restrict__ xp, float* __restrict__ yp)
{
    const int which = blockIdx.z;
    const float* __restrict__ A  = which ? y : x;
    const float* __restrict__ Bw = W1 + which * DD * DD;
    float* __restrict__ outp = which ? yp : xp;

    __shared__ float As[32 * 36];   // As[k][m] (transposed), stride 36
    __shared__ float Bs[32 * 68];   // Bs[k][n], stride 68

    const int tid = threadIdx.x;
    const int tx = tid & 15, ty = tid >> 4;
    const int mBase = blockIdx.x * 32;
    const int nBase = blockIdx.y * 64;

    const float4* A4 = (const float4*)A;
    const float4* B4 = (const float4*)Bw;

    const int ar = tid >> 3;       // 0..31  A row (m)
    const int ac = tid & 7;        // 0..7   A float4 col (k/4)
    const int br = tid >> 4;       // 0..15  B k-row (and +16)
    const int bc = tid & 15;       // 0..15  B float4 col (n/4)

    float4 pa, pb0, pb1;
    pa  = A4[(mBase + ar) * 64 + 0 * 8 + ac];
    pb0 = B4[(0 * 32 + br) * 64 + (nBase >> 2) + bc];
    pb1 = B4[(0 * 32 + br + 16) * 64 + (nBase >> 2) + bc];

    // acc[i] split into lo/hi f2 halves of the 4-wide n block -> v_pk_fma
    f2 accl[2] = {}, acch[2] = {};

    for (int kc = 0; kc < 8; ++kc) {
        __syncthreads();
        {
            float av[4] = {pa.x, pa.y, pa.z, pa.w};
            #pragma unroll
            for (int q = 0; q < 4; ++q) As[(ac * 4 + q) * 36 + ar] = av[q];
            *(float4*)&Bs[br * 68 + bc * 4] = pb0;
            *(float4*)&Bs[(br + 16) * 68 + bc * 4] = pb1;
        }
        __syncthreads();
        if (kc < 7) {
            pa  = A4[(mBase + ar) * 64 + (kc + 1) * 8 + ac];
            pb0 = B4[((kc + 1) * 32 + br) * 64 + (nBase >> 2) + bc];
            pb1 = B4[((kc + 1) * 32 + br + 16) * 64 + (nBase >> 2) + bc];
        }
        #pragma unroll
        for (int k = 0; k < 32; ++k) {
            f2 a = *(const f2*)&As[k * 36 + ty * 2];
            float4 b = *(const float4*)&Bs[k * 68 + tx * 4];
            f2 blo = {b.x, b.y};
            f2 bhi = {b.z, b.w};
            f2 a0 = {a.x, a.x};     // splat -> op_sel, free in VOP3P
            f2 a1 = {a.y, a.y};
            accl[0] = __builtin_elementwise_fma(a0, blo, accl[0]);
            acch[0] = __builtin_elementwise_fma(a0, bhi, acch[0]);
            accl[1] = __builtin_elementwise_fma(a1, blo, accl[1]);
            acch[1] = __builtin_elementwise_fma(a1, bhi, acch[1]);
        }
    }

    float4 bias = make_float4(0.f, 0.f, 0.f, 0.f);
    if (which == 0) bias = *((const float4*)b1 + (nBase >> 2) + tx);
    #pragma unroll
    for (int i = 0; i < 2; ++i) {
        float4 o;
        o.x = accl[i].x + bias.x;
        o.y = accl[i].y + bias.y;
        o.z = acch[i].x + bias.z;
        o.w = acch[i].y + bias.w;
        ((float4*)outp)[(mBase + ty * 2 + i) * (DD / 4) + (nBase >> 2) + tx] = o;
    }
}

// ---------------------------------------------------------------------------
// Kernel 2: o[b,n,m] = sum_d gelu(xp[b,n,d] + yp[b,m,d]) * W2[d] + b2
// R13: NO-LDS cache-direct variant of R12. Rationale: three configs (R11,
// R12) all pin cross at 52-53 us with busy ~36 us vs a 34 us VALU-issue
// floor (10 pk x 4cyc per f2); the ~16 us idle tracks the stage->barrier->
// compute rhythm (barrier skew, post-barrier lgkm bursts, write drains),
// not occupancy. xp+yp = 4 MB -- L2-resident 8x over. Guide common-mistake
// #7: staging L2-fit data is pure overhead. So: read x/y/W2 straight from
// global. Zero __shared__, zero barriers, zero staging insts. Waves fully
// independent; global loads ride vmcnt and hoist 2-3 iters deep under the
// 64-VGPR/8-wave budget. Per-thread math and summation order BIT-IDENTICAL
// to R12 (absmax must stay 0.00390625 exactly).
// x reads: 2 addrs/wave (broadcast). y reads: 32 lines/wave-op (~27 us L1
// lookup, overlapped with 34 us VALU). Watch: dur>=52 & VALUBusy<70 =>
// scatter-bound => revert to R12 and declare.
// Gelu: trans-free deg-13 odd Chebyshev erf poly (R8-proven); 0.5 folded
// into the epilogue.
// ---------------------------------------------------------------------------
#define GC1  0.79687960f
#define GC3  (-0.13053245f)
#define GC5  0.018104800f
#define GC7  (-0.0017319756f)
#define GC9  1.05671e-4f
#define GC11 (-3.64829e-6f)
#define GC13 5.37117e-8f

__global__ __launch_bounds__(512, 4) void cross_kernel(
    const float* __restrict__ xp, const float* __restrict__ yp,
    const float* __restrict__ W2, const float* __restrict__ b2,
    float* __restrict__ o)
{
    const int tid   = threadIdx.x;
    const int b     = blockIdx.z;
    const int mBase = blockIdx.x * 32;
    const int nBase = blockIdx.y * 32;
    const int tx = tid & 31;       // m col (single)
    const int ty = tid >> 5;       // 0..15: n rows ty, ty+16

    // per-thread row pointers (64 float4 each over d)
    const float4* __restrict__ xr0p =
        (const float4*)xp + (size_t)(b * N1 + nBase + ty) * (DD / 4);
    const float4* __restrict__ xr1p = xr0p + 16 * (DD / 4);
    const float4* __restrict__ yrp  =
        (const float4*)yp + (size_t)(b * N2 + mBase + tx) * (DD / 4);
    const float4* __restrict__ W2v = (const float4*)W2;

    f2 accA[2] = {};   // lo-half accumulators (i = n-row 0/1)
    f2 accB[2] = {};   // hi-half accumulators

    #pragma unroll 16
    for (int c4 = 0; c4 < 64; ++c4) {
        float4 wv  = W2v[c4];          // uniform -> s_load
        f2 wlo = {wv.x, wv.y};
        f2 whi = {wv.z, wv.w};
        float4 yr  = yrp[c4];          // per-lane row: 32-line scatter, L1/L2
        f2 ylo = {yr.x, yr.y};
        f2 yhi = {yr.z, yr.w};
        float4 xr0 = xr0p[c4];         // 2 addrs/wave: broadcast
        float4 xr1 = xr1p[c4];
        #pragma unroll
        for (int i = 0; i < 2; ++i) {
            float4 xr = i ? xr1 : xr0;
            f2 xlo = {xr.x, xr.y};
            f2 xhi = {xr.z, xr.w};
            f2 hlo = xlo + ylo;
            f2 hhi = xhi + yhi;
            f2 ulo = hlo * hlo;
            f2 uhi = hhi * hhi;
            // q = Q(u): erf(h/sqrt2) = h*Q(h^2), Horner deg-6 in u
            f2 qlo = __builtin_elementwise_fma(ulo, (f2)GC13, (f2)GC11);
            f2 qhi = __builtin_elementwise_fma(uhi, (f2)GC13, (f2)GC11);
            qlo = __builtin_elementwise_fma(qlo, ulo, (f2)GC9);
            qhi = __builtin_elementwise_fma(qhi, uhi, (f2)GC9);
            qlo = __builtin_elementwise_fma(qlo, ulo, (f2)GC7);
            qhi = __builtin_elementwise_fma(qhi, uhi, (f2)GC7);
            qlo = __builtin_elementwise_fma(qlo, ulo, (f2)GC5);
            qhi = __builtin_elementwise_fma(qhi, uhi, (f2)GC5);
            qlo = __builtin_elementwise_fma(qlo, ulo, (f2)GC3);
            qhi = __builtin_elementwise_fma(qhi, uhi, (f2)GC3);
            qlo = __builtin_elementwise_fma(qlo, ulo, (f2)GC1);
            qhi = __builtin_elementwise_fma(qhi, uhi, (f2)GC1);
            // gelu = 0.5*(h + u*q); the 0.5 is applied in the epilogue
            f2 slo = __builtin_elementwise_fma(ulo, qlo, hlo);
            f2 shi = __builtin_elementwise_fma(uhi, qhi, hhi);
            accA[i] = __builtin_elementwise_fma(slo, wlo, accA[i]);
            accB[i] = __builtin_elementwise_fma(shi, whi, accB[i]);
        }
    }

    const float bias2 = b2[0];
    const size_t base = ((size_t)(b * N1 + nBase)) * N2 + mBase;
    #pragma unroll
    for (int i = 0; i < 2; ++i) {
        o[base + (size_t)(ty + 16 * i) * N2 + tx] =
            0.5f * (accA[i].x + accA[i].y + accB[i].x + accB[i].y) + bias2;
    }
}

extern "C" void kernel_launch(void* const* d_in, const int* in_sizes, int n_in,
                              void* d_out, int out_size, void* d_ws, size_t ws_size,
                              hipStream_t stream)
{
    const float* x  = (const float*)d_in[0];
    const float* y  = (const float*)d_in[1];
    const float* W1 = (const float*)d_in[2];
    const float* b1 = (const float*)d_in[3];
    const float* W2 = (const float*)d_in[4];
    const float* b2 = (const float*)d_in[5];
    float* o  = (float*)d_out;
    float* xp = (float*)d_ws;                 // 2048*256 floats = 2 MB
    float* yp = xp + (BB * N1) * DD;          // next 2 MB

    dim3 g1(64, 4, 2);               // (M/32, N/64, which) = 512 blocks
    proj_kernel<<<g1, 256, 0, stream>>>(x, y, W1, b1, xp, yp);

    dim3 g2(N2 / 32, N1 / 32, BB);   // 16 x 16 x 4 = 1024 eight-wave blocks
    cross_kernel<<<g2, 512, 0, stream>>>(xp, yp, W2, b2, o);
}

// Round 14
// 124.643 us; speedup vs baseline: 1.3326x; 1.3326x over previous
//
#include <hip/hip_runtime.h>

#define DD 256   // feature dim
#define N1 512
#define N2 512
#define BB 4

// Packed fp32: gfx950 (gfx90a+) PackedFP32Ops; the compiler selects
// v_pk_{add,mul,fma}_f32 from <2 x float> vector IR.
typedef float f2 __attribute__((ext_vector_type(2)));

// ---------------------------------------------------------------------------
// Kernel 1: projection GEMMs. R2 version verbatim: 32x64 tile / 256 threads /
// 2x4 register blocking (packed), K-chunks of 32, register-prefetch double
// buffering, 512 blocks = 2/CU. Proven; leave alone.
// ---------------------------------------------------------------------------
__global__ __launch_bounds__(256) void proj_kernel(
    const float* __restrict__ x, const float* __restrict__ y,
    const float* __restrict__ W1, const float* __restrict__ b1,
    float* __restrict__ xp, float* __restrict__ yp)
{
    const int which = blockIdx.z;
    const float* __restrict__ A  = which ? y : x;
    const float* __restrict__ Bw = W1 + which * DD * DD;
    float* __restrict__ outp = which ? yp : xp;

    __shared__ float As[32 * 36];   // As[k][m] (transposed), stride 36
    __shared__ float Bs[32 * 68];   // Bs[k][n], stride 68

    const int tid = threadIdx.x;
    const int tx = tid & 15, ty = tid >> 4;
    const int mBase = blockIdx.x * 32;
    const int nBase = blockIdx.y * 64;

    const float4* A4 = (const float4*)A;
    const float4* B4 = (const float4*)Bw;

    const int ar = tid >> 3;       // 0..31  A row (m)
    const int ac = tid & 7;        // 0..7   A float4 col (k/4)
    const int br = tid >> 4;       // 0..15  B k-row (and +16)
    const int bc = tid & 15;       // 0..15  B float4 col (n/4)

    float4 pa, pb0, pb1;
    pa  = A4[(mBase + ar) * 64 + 0 * 8 + ac];
    pb0 = B4[(0 * 32 + br) * 64 + (nBase >> 2) + bc];
    pb1 = B4[(0 * 32 + br + 16) * 64 + (nBase >> 2) + bc];

    // acc[i] split into lo/hi f2 halves of the 4-wide n block -> v_pk_fma
    f2 accl[2] = {}, acch[2] = {};

    for (int kc = 0; kc < 8; ++kc) {
        __syncthreads();
        {
            float av[4] = {pa.x, pa.y, pa.z, pa.w};
            #pragma unroll
            for (int q = 0; q < 4; ++q) As[(ac * 4 + q) * 36 + ar] = av[q];
            *(float4*)&Bs[br * 68 + bc * 4] = pb0;
            *(float4*)&Bs[(br + 16) * 68 + bc * 4] = pb1;
        }
        __syncthreads();
        if (kc < 7) {
            pa  = A4[(mBase + ar) * 64 + (kc + 1) * 8 + ac];
            pb0 = B4[((kc + 1) * 32 + br) * 64 + (nBase >> 2) + bc];
            pb1 = B4[((kc + 1) * 32 + br + 16) * 64 + (nBase >> 2) + bc];
        }
        #pragma unroll
        for (int k = 0; k < 32; ++k) {
            f2 a = *(const f2*)&As[k * 36 + ty * 2];
            float4 b = *(const float4*)&Bs[k * 68 + tx * 4];
            f2 blo = {b.x, b.y};
            f2 bhi = {b.z, b.w};
            f2 a0 = {a.x, a.x};     // splat -> op_sel, free in VOP3P
            f2 a1 = {a.y, a.y};
            accl[0] = __builtin_elementwise_fma(a0, blo, accl[0]);
            acch[0] = __builtin_elementwise_fma(a0, bhi, acch[0]);
            accl[1] = __builtin_elementwise_fma(a1, blo, accl[1]);
            acch[1] = __builtin_elementwise_fma(a1, bhi, acch[1]);
        }
    }

    float4 bias = make_float4(0.f, 0.f, 0.f, 0.f);
    if (which == 0) bias = *((const float4*)b1 + (nBase >> 2) + tx);
    #pragma unroll
    for (int i = 0; i < 2; ++i) {
        float4 o;
        o.x = accl[i].x + bias.x;
        o.y = accl[i].y + bias.y;
        o.z = acch[i].x + bias.z;
        o.w = acch[i].y + bias.w;
        ((float4*)outp)[(mBase + ty * 2 + i) * (DD / 4) + (nBase >> 2) + tx] = o;
    }
}

// ---------------------------------------------------------------------------
// Kernel 2: o[b,n,m] = sum_d gelu(xp[b,n,d] + yp[b,m,d]) * W2[d] + b2
// R14: 2x2 REGISTER BLOCKING on the R11 static-dbuf skeleton.
// Ledger after R13: VALU demand ~34 us/SIMD, LDS-read demand ~31 us/CU
// (3 ds_read_b128 per 8 evals) -- two pipes at ~90% parity => the robust
// ~16 us jitter-idle seen in R11/R12. R13 (no LDS) proved staging is the
// scatter-dedup, not removable. Fix: 4 outputs/thread (2n x 2m) -> per c4:
// 2 x-reads + 2 y-reads for 16 evals = 0.25 reads/eval (-33%), LDS demand
// ~20 us << VALU 34 us -> single-pipe regime. W2 s_load amortized 2x.
// 256 threads, 32n x 32m tile, 1024 blocks = 4 blocks/CU (LDS 34816 B
// exactly fills the 4-block budget) = 16 waves/CU.
// Static-NAMED dbuf only (runtime-indexed condemned: R1/R9). 5 barriers.
// Gelu: deg-13 odd Chebyshev erf poly, per-element math and per-output
// summation order BIT-IDENTICAL to R12 -> absmax must stay 0.00390625.
// Read conflicts: xr 4-addr broadcast (free), yr 2-way (free, m136);
// writes = R11's proven pattern (measured 0 conflicts).
// TRIPWIRE: FETCH > 15 MB or VGPR > 96 => spill => revert to R12.
// ---------------------------------------------------------------------------
#define GC1  0.79687960f
#define GC3  (-0.13053245f)
#define GC5  0.018104800f
#define GC7  (-0.0017319756f)
#define GC9  1.05671e-4f
#define GC11 (-3.64829e-6f)
#define GC13 5.37117e-8f

__global__ __launch_bounds__(256, 4) void cross_kernel(
    const float* __restrict__ xp, const float* __restrict__ yp,
    const float* __restrict__ W2, const float* __restrict__ b2,
    float* __restrict__ o)
{
    __shared__ float xsA[32 * 68];
    __shared__ float xsB[32 * 68];
    __shared__ float ysA[32 * 68];
    __shared__ float ysB[32 * 68];

    const int tid   = threadIdx.x;
    const int b     = blockIdx.z;
    const int mBase = blockIdx.x * 32;
    const int nBase = blockIdx.y * 32;
    const int tx = tid & 15;       // m cols tx, tx+16
    const int ty = tid >> 4;       // n rows ty, ty+16

    const float4* xp4 = (const float4*)xp + (b * N1 + nBase) * (DD / 4);
    const float4* yp4 = (const float4*)yp + (b * N2 + mBase) * (DD / 4);
    const float4* __restrict__ W2v = (const float4*)W2;

    // staging per 64-d chunk: xs,ys = 32 rows x 16 f4, 2 f4/thread each
    const int sr = tid >> 3;            // 0..31  row
    const int sc = tid & 7;             // 0..7   f4 col (and +8)

    float4 px0, px1, py0, py1;
    f2 accA[2][2] = {};   // lo-half accumulators [i][j]
    f2 accB[2][2] = {};   // hi-half accumulators [i][j]

#define STAGE_LOAD(CH)                                      \
    px0 = xp4[sr * 64 + (CH) * 16 + sc];                    \
    px1 = xp4[sr * 64 + (CH) * 16 + sc + 8];                \
    py0 = yp4[sr * 64 + (CH) * 16 + sc];                    \
    py1 = yp4[sr * 64 + (CH) * 16 + sc + 8];

#define STAGE_WRITE(XS, YS)                                 \
    *(float4*)&XS[sr * 68 + sc * 4]       = px0;            \
    *(float4*)&XS[sr * 68 + (sc + 8) * 4] = px1;            \
    *(float4*)&YS[sr * 68 + sc * 4]       = py0;            \
    *(float4*)&YS[sr * 68 + (sc + 8) * 4] = py1;

#define COMPUTE(XS, YS, KC)                                                    \
    _Pragma("unroll")                                                          \
    for (int c4 = 0; c4 < 16; ++c4) {                                          \
        float4 wv = W2v[(KC) * 16 + c4];                                       \
        f2 wlo = {wv.x, wv.y};                                                 \
        f2 whi = {wv.z, wv.w};                                                 \
        float4 xr[2], yr[2];                                                   \
        xr[0] = *(const float4*)&XS[ty * 68 + c4 * 4];                         \
        xr[1] = *(const float4*)&XS[(ty + 16) * 68 + c4 * 4];                  \
        yr[0] = *(const float4*)&YS[tx * 68 + c4 * 4];                         \
        yr[1] = *(const float4*)&YS[(tx + 16) * 68 + c4 * 4];                  \
        _Pragma("unroll")                                                      \
        for (int i = 0; i < 2; ++i) {                                          \
            f2 xlo = {xr[i].x, xr[i].y};                                       \
            f2 xhi = {xr[i].z, xr[i].w};                                       \
            _Pragma("unroll")                                                  \
            for (int j = 0; j < 2; ++j) {                                      \
                f2 ylo = {yr[j].x, yr[j].y};                                   \
                f2 yhi = {yr[j].z, yr[j].w};                                   \
                f2 hlo = xlo + ylo;                                            \
                f2 hhi = xhi + yhi;                                            \
                f2 ulo = hlo * hlo;                                            \
                f2 uhi = hhi * hhi;                                            \
                f2 qlo = __builtin_elementwise_fma(ulo, (f2)GC13, (f2)GC11);   \
                f2 qhi = __builtin_elementwise_fma(uhi, (f2)GC13, (f2)GC11);   \
                qlo = __builtin_elementwise_fma(qlo, ulo, (f2)GC9);            \
                qhi = __builtin_elementwise_fma(qhi, uhi, (f2)GC9);            \
                qlo = __builtin_elementwise_fma(qlo, ulo, (f2)GC7);            \
                qhi = __builtin_elementwise_fma(qhi, uhi, (f2)GC7);            \
                qlo = __builtin_elementwise_fma(qlo, ulo, (f2)GC5);            \
                qhi = __builtin_elementwise_fma(qhi, uhi, (f2)GC5);            \
                qlo = __builtin_elementwise_fma(qlo, ulo, (f2)GC3);            \
                qhi = __builtin_elementwise_fma(qhi, uhi, (f2)GC3);            \
                qlo = __builtin_elementwise_fma(qlo, ulo, (f2)GC1);            \
                qhi = __builtin_elementwise_fma(qhi, uhi, (f2)GC1);            \
                f2 slo = __builtin_elementwise_fma(ulo, qlo, hlo);             \
                f2 shi = __builtin_elementwise_fma(uhi, qhi, hhi);             \
                accA[i][j] = __builtin_elementwise_fma(slo, wlo, accA[i][j]);  \
                accB[i][j] = __builtin_elementwise_fma(shi, whi, accB[i][j]);  \
            }                                                                  \
        }                                                                      \
    }

    STAGE_LOAD(0)
    STAGE_WRITE(xsA, ysA)
    __syncthreads();                    // B0: bufA(chunk0) ready

    STAGE_LOAD(1)                       // global latency hides under compute
    COMPUTE(xsA, ysA, 0)
    STAGE_WRITE(xsB, ysB)
    __syncthreads();                    // B1: bufB(chunk1) ready, bufA free

    STAGE_LOAD(2)
    COMPUTE(xsB, ysB, 1)
    STAGE_WRITE(xsA, ysA)
    __syncthreads();                    // B2: bufA(chunk2) ready, bufB free

    STAGE_LOAD(3)
    COMPUTE(xsA, ysA, 2)
    STAGE_WRITE(xsB, ysB)
    __syncthreads();                    // B3: bufB(chunk3) ready

    COMPUTE(xsB, ysB, 3)

#undef STAGE_LOAD
#undef STAGE_WRITE
#undef COMPUTE

    const float bias2 = b2[0];
    const size_t base = ((size_t)(b * N1 + nBase)) * N2 + mBase;
    #pragma unroll
    for (int i = 0; i < 2; ++i) {
        #pragma unroll
        for (int j = 0; j < 2; ++j) {
            o[base + (size_t)(ty + 16 * i) * N2 + (tx + 16 * j)] =
                0.5f * (accA[i][j].x + accA[i][j].y +
                        accB[i][j].x + accB[i][j].y) + bias2;
        }
    }
}

extern "C" void kernel_launch(void* const* d_in, const int* in_sizes, int n_in,
                              void* d_out, int out_size, void* d_ws, size_t ws_size,
                              hipStream_t stream)
{
    const float* x  = (const float*)d_in[0];
    const float* y  = (const float*)d_in[1];
    const float* W1 = (const float*)d_in[2];
    const float* b1 = (const float*)d_in[3];
    const float* W2 = (const float*)d_in[4];
    const float* b2 = (const float*)d_in[5];
    float* o  = (float*)d_out;
    float* xp = (float*)d_ws;                 // 2048*256 floats = 2 MB
    float* yp = xp + (BB * N1) * DD;          // next 2 MB

    dim3 g1(64, 4, 2);               // (M/32, N/64, which) = 512 blocks
    proj_kernel<<<g1, 256, 0, stream>>>(x, y, W1, b1, xp, yp);

    dim3 g2(N2 / 32, N1 / 32, BB);   // 16 x 16 x 4 = 1024 four-wave blocks
    cross_kernel<<<g2, 256, 0, stream>>>(xp, yp, W2, b2, o);
}